// Round 5
// baseline (918.572 us; speedup 1.0000x reference)
//
#include <hip/hip_runtime.h>
#include <math.h>

typedef __attribute__((ext_vector_type(8))) short short8;
typedef __attribute__((ext_vector_type(8))) unsigned short ushort8;
typedef __attribute__((ext_vector_type(4))) float f32x4;

__device__ __forceinline__ float b2f(unsigned short h) {
    union { unsigned int u; float f; } c; c.u = ((unsigned int)h) << 16; return c.f;
}
__device__ __forceinline__ unsigned short f2b(float x) {
    union { float f; unsigned int u; } c; c.f = x;
    unsigned int r = c.u + 0x7fffu + ((c.u >> 16) & 1u);
    return (unsigned short)(r >> 16);
}

// ---------------- cast f32 -> bf16 (vectorized) ----------------
__global__ __launch_bounds__(256) void cast_f2b(const float* __restrict__ in,
                                                unsigned short* __restrict__ out, int n4) {
    int i = blockIdx.x * 256 + threadIdx.x;
    if (i >= n4) return;
    float4 f = ((const float4*)in)[i];
    ushort4 o; o.x = f2b(f.x); o.y = f2b(f.y); o.z = f2b(f.z); o.w = f2b(f.w);
    ((ushort4*)out)[i] = o;
}

// ---------------- wave-per-row LayerNorm ----------------
template <int DD, bool INB, bool OUTB>
__global__ __launch_bounds__(256) void ln_rows(const void* __restrict__ in_, void* __restrict__ out_,
                                               const float* __restrict__ g, const float* __restrict__ bb,
                                               int nrows) {
    const int wv = threadIdx.x >> 6, l = threadIdx.x & 63;
    const int row = blockIdx.x * 4 + wv;
    if (row >= nrows) return;
    constexpr int NC = DD / 256;
    float v[DD / 64];
    if constexpr (INB) {
        const ushort4* in = (const ushort4*)((const unsigned short*)in_ + (size_t)row * DD);
#pragma unroll
        for (int c = 0; c < NC; ++c) {
            ushort4 u = in[l + 64 * c];
            v[4*c] = b2f(u.x); v[4*c+1] = b2f(u.y); v[4*c+2] = b2f(u.z); v[4*c+3] = b2f(u.w);
        }
    } else {
        const float4* in = (const float4*)((const float*)in_ + (size_t)row * DD);
#pragma unroll
        for (int c = 0; c < NC; ++c) {
            float4 u = in[l + 64 * c];
            v[4*c] = u.x; v[4*c+1] = u.y; v[4*c+2] = u.z; v[4*c+3] = u.w;
        }
    }
    float s = 0.f, s2 = 0.f;
#pragma unroll
    for (int i = 0; i < DD / 64; ++i) { s += v[i]; s2 += v[i] * v[i]; }
#pragma unroll
    for (int o = 32; o > 0; o >>= 1) { s += __shfl_xor(s, o, 64); s2 += __shfl_xor(s2, o, 64); }
    const float mu = s * (1.0f / DD);
    const float var = s2 * (1.0f / DD) - mu * mu;
    const float rs = rsqrtf(var + 1e-5f);
    if constexpr (OUTB) {
        ushort4* out = (ushort4*)((unsigned short*)out_ + (size_t)row * DD);
#pragma unroll
        for (int c = 0; c < NC; ++c) {
            int e = (l + 64 * c) * 4;
            ushort4 o4;
            o4.x = f2b((v[4*c]   - mu) * rs * g[e]   + bb[e]);
            o4.y = f2b((v[4*c+1] - mu) * rs * g[e+1] + bb[e+1]);
            o4.z = f2b((v[4*c+2] - mu) * rs * g[e+2] + bb[e+2]);
            o4.w = f2b((v[4*c+3] - mu) * rs * g[e+3] + bb[e+3]);
            out[l + 64 * c] = o4;
        }
    } else {
        float4* out = (float4*)((float*)out_ + (size_t)row * DD);
#pragma unroll
        for (int c = 0; c < NC; ++c) {
            int e = (l + 64 * c) * 4;
            float4 o4;
            o4.x = (v[4*c]   - mu) * rs * g[e]   + bb[e];
            o4.y = (v[4*c+1] - mu) * rs * g[e+1] + bb[e+1];
            o4.z = (v[4*c+2] - mu) * rs * g[e+2] + bb[e+2];
            o4.w = (v[4*c+3] - mu) * rs * g[e+3] + bb[e+3];
            out[l + 64 * c] = o4;
        }
    }
}

// ---------------- ln_stats: per-row (rs, rs*mu) of raw bf16 kv ----------------
__global__ __launch_bounds__(256) void ln_stats(const unsigned short* __restrict__ kv,
                                                float2* __restrict__ stats, int nrows) {
    const int wv = threadIdx.x >> 6, l = threadIdx.x & 63;
    const int row = blockIdx.x * 4 + wv;
    if (row >= nrows) return;
    const ushort4* in = (const ushort4*)(kv + (size_t)row * 768);
    float s = 0.f, s2 = 0.f;
#pragma unroll
    for (int c = 0; c < 3; ++c) {
        ushort4 u = in[l + 64 * c];
        float a = b2f(u.x), b = b2f(u.y), cc = b2f(u.z), d = b2f(u.w);
        s += a + b + cc + d;
        s2 += a * a + b * b + cc * cc + d * d;
    }
#pragma unroll
    for (int o = 32; o > 0; o >>= 1) { s += __shfl_xor(s, o, 64); s2 += __shfl_xor(s2, o, 64); }
    const float mu = s * (1.0f / 768.0f);
    const float var = s2 * (1.0f / 768.0f) - mu * mu;
    const float rs = rsqrtf(var + 1e-5f);
    if (l == 0) stats[row] = make_float2(rs, rs * mu);
}

// ---------------- qp = LN(queries) @ wq^T + bq ----------------
__global__ __launch_bounds__(256) void qp_kernel(const float* __restrict__ qn, const float* __restrict__ wq,
                                                 const float* __restrict__ bq, float* __restrict__ qp) {
    int q = blockIdx.x / 3;
    int col = (blockIdx.x % 3) * 256 + threadIdx.x;
    const float4* a = (const float4*)(qn + q * 768);
    const float4* wr = (const float4*)(wq + (size_t)col * 768);
    float s = 0.f;
#pragma unroll 8
    for (int k = 0; k < 192; ++k) {
        float4 xx = a[k], yy = wr[k];
        s += xx.x * yy.x + xx.y * yy.y + xx.z * yy.z + xx.w * yy.w;
    }
    qp[q * 768 + col] = s + bq[col];
}

// ---------------- qkg[hq][e] = g[e]*scale*sum_d qp[..]*wk[..][e]; t[hq] = sum_e qkg ----------------
__global__ __launch_bounds__(256) void qk_build(const float* __restrict__ qp, const float* __restrict__ wk,
                                                const float* __restrict__ g,
                                                unsigned short* __restrict__ qkg, float* __restrict__ tout) {
    __shared__ float red[4];
    const int hq = blockIdx.x, h = hq >> 3, q = hq & 7;
    const int tid = threadIdx.x;
    const float* qv = qp + q * 768 + h * 96;
    float tsum = 0.f;
#pragma unroll
    for (int c = 0; c < 3; ++c) {
        int e = tid + 256 * c;
        float s = 0.f;
        for (int d = 0; d < 96; ++d) s += qv[d] * wk[(size_t)(h * 96 + d) * 768 + e];
        unsigned short bv = f2b(s * 0.10206207262f * g[e]);
        qkg[hq * 768 + e] = bv;
        tsum += b2f(bv);
    }
#pragma unroll
    for (int o = 32; o > 0; o >>= 1) tsum += __shfl_xor(tsum, o, 64);
    if ((tid & 63) == 0) red[tid >> 6] = tsum;
    __syncthreads();
    if (tid == 0) tout[hq] = red[0] + red[1] + red[2] + red[3];
}

// ---------------- MFMA GEMM machinery ----------------
__device__ __forceinline__ void gll16(const void* g, void* l) {
    __builtin_amdgcn_global_load_lds((const __attribute__((address_space(1))) unsigned int*)g,
                                     (__attribute__((address_space(3))) unsigned int*)l, 16, 0, 0);
}

template <int ROWS>
__device__ __forceinline__ void stage_rows(const unsigned short* gbase, int ldg,
                                           unsigned short* lds, int tid) {
    int wuni = tid & ~63;
#pragma unroll
    for (int it = 0; it < ROWS / 32; ++it) {
        int s = it * 256 + tid;
        int r = s >> 3, c = s & 7;
        int cc = c ^ (r & 7);  // inverse swizzle on global source; LDS stays gll-linear
        gll16(gbase + (size_t)r * ldg + cc * 8, lds + (size_t)(it * 256 + wuni) * 8);
    }
}

// EPI: 0 bias->bf16 | 1 bias+queries[row&7]->f32 | 2 bias+gelu->bf16 | 3 bias+aux[row]->bf16 | 4 bias->f32
template <int EPI>
__global__ __launch_bounds__(256) void gemm_bf16(
    const unsigned short* __restrict__ A, const unsigned short* __restrict__ W,
    const float* __restrict__ bias, void* __restrict__ out,
    const float* __restrict__ aux, int K, int N) {
    __shared__ __align__(16) unsigned short lA[128 * 64];
    __shared__ __align__(16) unsigned short lB[128 * 64];
    const int tid = threadIdx.x;
    const int l = tid & 63, w = tid >> 6;
    int gx = gridDim.x;
    int lid = blockIdx.y * gx + blockIdx.x;
    int nwg = gx * gridDim.y;
    int idx = (nwg & 7) ? lid : ((lid & 7) * (nwg >> 3) + (lid >> 3));
    const int bm0 = (idx / gx) * 128, bn0 = (idx % gx) * 128;
    const int wm = (w >> 1) * 64, wn = (w & 1) * 64;
    const int l15 = l & 15, lk = l >> 4;
    f32x4 acc[4][4] = {};
    const int nk = K >> 6;
    const unsigned short* Abase = A + (size_t)bm0 * K;
    const unsigned short* Wbase = W + (size_t)bn0 * K;
    for (int kt = 0; kt < nk; ++kt) {
        stage_rows<128>(Abase + kt * 64, K, lA, tid);
        stage_rows<128>(Wbase + kt * 64, K, lB, tid);
        __syncthreads();
        short8 af[4], bf[4];
#pragma unroll
        for (int kk = 0; kk < 2; ++kk) {
#pragma unroll
            for (int mf = 0; mf < 4; ++mf) {
                int r = wm + mf * 16 + l15;
                int c = (kk * 4 + lk) ^ (r & 7);
                af[mf] = *(const short8*)(lA + r * 64 + c * 8);
            }
#pragma unroll
            for (int nf = 0; nf < 4; ++nf) {
                int r = wn + nf * 16 + l15;
                int c = (kk * 4 + lk) ^ (r & 7);
                bf[nf] = *(const short8*)(lB + r * 64 + c * 8);
            }
#pragma unroll
            for (int mf = 0; mf < 4; ++mf)
#pragma unroll
                for (int nf = 0; nf < 4; ++nf)
                    acc[mf][nf] = __builtin_amdgcn_mfma_f32_16x16x32_bf16(af[mf], bf[nf], acc[mf][nf], 0, 0, 0);
        }
        __syncthreads();
    }
    const int row0 = bm0 + wm + (lk << 2);
    const int col0 = bn0 + wn + l15;
#pragma unroll
    for (int nf = 0; nf < 4; ++nf) {
        int col = col0 + nf * 16;
        float bv = bias[col];
#pragma unroll
        for (int mf = 0; mf < 4; ++mf) {
#pragma unroll
            for (int r = 0; r < 4; ++r) {
                int row = row0 + mf * 16 + r;
                float v = acc[mf][nf][r] + bv;
                size_t idx2 = (size_t)row * N + col;
                if constexpr (EPI == 0) {
                    ((unsigned short*)out)[idx2] = f2b(v);
                } else if constexpr (EPI == 1) {
                    v += aux[(row & 7) * N + col];
                    ((float*)out)[idx2] = v;
                } else if constexpr (EPI == 2) {
                    v = 0.5f * v * (1.0f + erff(v * 0.70710678118f));
                    ((unsigned short*)out)[idx2] = f2b(v);
                } else if constexpr (EPI == 3) {
                    v += aux[idx2];
                    ((unsigned short*)out)[idx2] = f2b(v);
                } else {
                    ((float*)out)[idx2] = v;
                }
            }
        }
    }
}

// ---------------- scores GEMM: S = rs_n * (kv_raw @ qkg^T) - u_n * t[hq] ----------------
__global__ __launch_bounds__(256) void gemm_scores(const unsigned short* __restrict__ A,
                                                   const unsigned short* __restrict__ Qk,
                                                   const float2* __restrict__ stats,
                                                   const float* __restrict__ tcol,
                                                   float* __restrict__ S) {
    __shared__ __align__(16) unsigned short lA[128 * 64];
    __shared__ __align__(16) unsigned short lB[64 * 64];
    const int tid = threadIdx.x;
    const int l = tid & 63, w = tid >> 6;
    int lid = blockIdx.x;
    int idx = (lid & 7) * (gridDim.x >> 3) + (lid >> 3);
    const int bm0 = idx * 128;
    const int wm = (w >> 1) * 64, wn = (w & 1) * 32;
    const int l15 = l & 15, lk = l >> 4;
    f32x4 acc[4][2] = {};
    const unsigned short* Abase = A + (size_t)bm0 * 768;
    for (int kt = 0; kt < 12; ++kt) {
        stage_rows<128>(Abase + kt * 64, 768, lA, tid);
        stage_rows<64>(Qk + kt * 64, 768, lB, tid);
        __syncthreads();
        short8 af[4], bf[2];
#pragma unroll
        for (int kk = 0; kk < 2; ++kk) {
#pragma unroll
            for (int mf = 0; mf < 4; ++mf) {
                int r = wm + mf * 16 + l15;
                int c = (kk * 4 + lk) ^ (r & 7);
                af[mf] = *(const short8*)(lA + r * 64 + c * 8);
            }
#pragma unroll
            for (int nf = 0; nf < 2; ++nf) {
                int r = wn + nf * 16 + l15;
                int c = (kk * 4 + lk) ^ (r & 7);
                bf[nf] = *(const short8*)(lB + r * 64 + c * 8);
            }
#pragma unroll
            for (int mf = 0; mf < 4; ++mf)
#pragma unroll
                for (int nf = 0; nf < 2; ++nf)
                    acc[mf][nf] = __builtin_amdgcn_mfma_f32_16x16x32_bf16(af[mf], bf[nf], acc[mf][nf], 0, 0, 0);
        }
        __syncthreads();
    }
    const int row0 = bm0 + wm + (lk << 2);
    const int col0 = wn + l15;
    const float tv0 = tcol[col0], tv1 = tcol[col0 + 16];
#pragma unroll
    for (int mf = 0; mf < 4; ++mf)
#pragma unroll
        for (int r = 0; r < 4; ++r) {
            int row = row0 + mf * 16 + r;
            float2 st = stats[row];
            S[(size_t)row * 64 + col0]      = st.x * acc[mf][0][r] - st.y * tv0;
            S[(size_t)row * 64 + col0 + 16] = st.x * acc[mf][1][r] - st.y * tv1;
        }
}

// ---------------- attn_ctx: fused softmax + mix + V/ctx projection, per b ----------------
// Per block b: softmax(S[b]) -> at (a*rs folded); 4 phases over e-chunks of 192:
//   stage kvT[192][64] -> mix MFMA (cmix chunk, LN epilogue) -> cmixL (LDS, swizzled)
//   -> ctx partial-K MFMA vs wv (global, L2-resident), accumulate in registers.
// Epilogue: ctx[b*8+q][h*96+c] = cacc + bv.  cmix never touches HBM.
__global__ __launch_bounds__(256) void attn_ctx(const unsigned short* __restrict__ kvr,
                                                const float* __restrict__ S,
                                                const float2* __restrict__ stats,
                                                const float* __restrict__ lg,
                                                const float* __restrict__ lb,
                                                const unsigned short* __restrict__ wvb,
                                                const float* __restrict__ bv,
                                                unsigned short* __restrict__ ctx) {
    __shared__ __align__(16) unsigned short at[64 * 64];       // 8 KB
    __shared__ __align__(16) unsigned short kvT[192 * 64];     // 24 KB; Sl unions into it
    __shared__ __align__(16) unsigned short cmixL[64 * 192];   // 24 KB
    __shared__ float dl[64];
    float* Sl = (float*)kvT;                                   // 12.25 KB <= 24 KB
    const int b = blockIdx.x;
    const int t = threadIdx.x, l = t & 63, w = t >> 6;
    const int l15 = l & 15, lk = l >> 4;

    for (int i = t; i < 3136; i += 256) Sl[i] = S[(size_t)b * 3136 + i];
    __syncthreads();
    if (w == 0) {
        float mx = -1e30f;
        for (int n = 0; n < 49; ++n) mx = fmaxf(mx, Sl[n * 64 + l]);
        float sum = 0.f;
        for (int n = 0; n < 49; ++n) sum += __expf(Sl[n * 64 + l] - mx);
        float inv = 1.0f / sum;
        float dacc = 0.f;
#pragma unroll
        for (int c = 0; c < 8; ++c) {
            int cc = c ^ (l & 7);
            for (int j = 0; j < 8; ++j) {
                int n = c * 8 + j;
                float av = 0.f;
                if (n < 49) {
                    float a = __expf(Sl[n * 64 + l] - mx) * inv;
                    float2 st = stats[(size_t)b * 49 + n];
                    av = a * st.x;
                    dacc += a * st.y;
                }
                at[l * 64 + cc * 8 + j] = f2b(av);
            }
        }
        dl[l] = dacc;
    }
    __syncthreads();  // softmax done; kvT may overwrite Sl

    // hoist dl for this thread's (mf, r) rows
    float dlv[4][4];
#pragma unroll
    for (int mf = 0; mf < 4; ++mf)
#pragma unroll
        for (int r = 0; r < 4; ++r) dlv[mf][r] = dl[mf * 16 + lk * 4 + r];

    f32x4 cacc[12] = {};
    const unsigned short* src = kvr + ((size_t)b * 49 + (l < 49 ? l : 0)) * 768;

#pragma unroll 1
    for (int ph = 0; ph < 4; ++ph) {
        // ---- stage kvT[e_local][n] for e_local in [0,192), swizzled n-chunks ----
#pragma unroll
        for (int i = 0; i < 6; ++i) {
            int e0 = w * 8 + i * 32;
            ushort8 v = {0, 0, 0, 0, 0, 0, 0, 0};
            if (l < 49) v = *(const ushort8*)(src + ph * 192 + e0);
#pragma unroll
            for (int j = 0; j < 8; ++j) {
                int e = e0 + j;
                kvT[e * 64 + (((l >> 3) ^ (e & 7)) << 3) + (l & 7)] = v[j];
            }
        }
        __syncthreads();

        // ---- mix MFMA: cmix[hq][e_local] for wave's 48-e slice ----
        f32x4 macc[4][3] = {};
#pragma unroll
        for (int ks = 0; ks < 2; ++ks) {
            short8 af[4], bf[3];
#pragma unroll
            for (int mf = 0; mf < 4; ++mf) {
                int r = mf * 16 + l15;
                af[mf] = *(const short8*)(at + r * 64 + (((ks * 4 + lk) ^ (r & 7)) << 3));
            }
#pragma unroll
            for (int nf = 0; nf < 3; ++nf) {
                int er = w * 48 + nf * 16 + l15;
                bf[nf] = *(const short8*)(kvT + er * 64 + (((ks * 4 + lk) ^ (er & 7)) << 3));
            }
#pragma unroll
            for (int mf = 0; mf < 4; ++mf)
#pragma unroll
                for (int nf = 0; nf < 3; ++nf)
                    macc[mf][nf] = __builtin_amdgcn_mfma_f32_16x16x32_bf16(af[mf], bf[nf], macc[mf][nf], 0, 0, 0);
        }
        // write cmix chunk to LDS with LN epilogue, XOR-swizzled for the ctx A-reads
#pragma unroll
        for (int nf = 0; nf < 3; ++nf) {
            int e_local = w * 48 + nf * 16 + l15;
            int e = ph * 192 + e_local;
            float gg = lg[e], bbv = lb[e];
            int c = e_local >> 3;
#pragma unroll
            for (int mf = 0; mf < 4; ++mf)
#pragma unroll
                for (int r = 0; r < 4; ++r) {
                    int hq = mf * 16 + lk * 4 + r;
                    int cs = (c & ~7) | ((c & 7) ^ (hq & 7));
                    cmixL[hq * 192 + cs * 8 + (e_local & 7)] =
                        f2b(gg * (macc[mf][nf][r] - dlv[mf][r]) + bbv);
                }
        }
        __syncthreads();

        // ---- ctx partial: per wave 2 h x 6 n-tiles, K = this 192-e chunk ----
#pragma unroll
        for (int jh = 0; jh < 2; ++jh) {
            int h = w * 2 + jh;
            int arow = h * 8 + l15;
            if (arow > 63) arow = 63;  // rows 8..15 of h=7 tile: garbage, discarded
            short8 af[6];
#pragma unroll
            for (int ks = 0; ks < 6; ++ks) {
                int c = ks * 4 + lk;
                int cs = (c & ~7) | ((c & 7) ^ (arow & 7));
                af[ks] = *(const short8*)(cmixL + arow * 192 + cs * 8);
            }
#pragma unroll
            for (int nt = 0; nt < 6; ++nt) {
                const unsigned short* wp = wvb + (size_t)(h * 96 + nt * 16 + l15) * 768 + ph * 192 + lk * 8;
#pragma unroll
                for (int ks = 0; ks < 6; ++ks) {
                    short8 bf = *(const short8*)(wp + ks * 32);
                    cacc[jh * 6 + nt] =
                        __builtin_amdgcn_mfma_f32_16x16x32_bf16(af[ks], bf, cacc[jh * 6 + nt], 0, 0, 0);
                }
            }
        }
        // no barrier: next stage writes kvT (last read before prev barrier);
        // next mix (after its barrier) is what overwrites cmixL
    }

    // ---- epilogue: ctx[b*8+q][h*96+c] ----
    if (lk < 2) {
#pragma unroll
        for (int j = 0; j < 12; ++j) {
            int h = w * 2 + j / 6, nt = j % 6;
            int col = h * 96 + nt * 16 + l15;
            float bbv = bv[col];
#pragma unroll
            for (int r = 0; r < 4; ++r) {
                int q = lk * 4 + r;
                ctx[((size_t)b * 8 + q) * 768 + col] = f2b(cacc[j][r] + bbv);
            }
        }
    }
}

// ---------------- host ----------------
extern "C" void kernel_launch(void* const* d_in, const int* in_sizes, int n_in,
                              void* d_out, int out_size, void* d_ws, size_t ws_size,
                              hipStream_t stream) {
    (void)in_sizes; (void)n_in; (void)out_size;
    const float* features      = (const float*)d_in[0];
    const float* input_proj_w  = (const float*)d_in[1];
    const float* input_proj_b  = (const float*)d_in[2];
    const float* queries       = (const float*)d_in[3];
    const float* ln_q_g        = (const float*)d_in[4];
    const float* ln_q_b        = (const float*)d_in[5];
    const float* ln_kv_g       = (const float*)d_in[6];
    const float* ln_kv_b       = (const float*)d_in[7];
    const float* in_proj_w     = (const float*)d_in[8];
    const float* in_proj_b     = (const float*)d_in[9];
    const float* out_proj_w    = (const float*)d_in[10];
    const float* out_proj_b    = (const float*)d_in[11];
    const float* ln_ff_g       = (const float*)d_in[12];
    const float* ln_ff_b       = (const float*)d_in[13];
    const float* ffn_w1        = (const float*)d_in[14];
    const float* ffn_b1        = (const float*)d_in[15];
    const float* ffn_w2        = (const float*)d_in[16];
    const float* ffn_b2        = (const float*)d_in[17];
    const float* output_proj_w = (const float*)d_in[18];
    const float* output_proj_b = (const float*)d_in[19];
    const float* final_g       = (const float*)d_in[20];
    const float* final_b       = (const float*)d_in[21];

    char* ws = (char*)d_ws;
    size_t off = 0;
    auto alloc = [&](size_t bytes) -> char* {
        char* r = ws + off; off += (bytes + 255) & ~(size_t)255; return r;
    };
    unsigned short* featb = (unsigned short*)alloc(100352ull * 320 * 2);    // 64 MB
    unsigned short* kvbuf = (unsigned short*)alloc(100352ull * 768 * 2);    // 154 MB (raw kv)
    float*          x     = (float*)alloc(16384ull * 768 * 4);              // 50 MB
    unsigned short* hn    = (unsigned short*)alloc(16384ull * 768 * 2);     // 25 MB
    unsigned short* f1    = (unsigned short*)alloc(16384ull * 768 * 2);     // 25 MB
    unsigned short* x2    = (unsigned short*)alloc(16384ull * 768 * 2);     // 25 MB
    float*          S     = (float*)alloc(100352ull * 64 * 4);              // 26 MB
    float2*         stats = (float2*)alloc(100352ull * 8);                  // 0.8 MB
    unsigned short* winb  = (unsigned short*)alloc(768ull * 320 * 2);
    unsigned short* wvb   = (unsigned short*)alloc(768ull * 768 * 2);
    unsigned short* woutb = (unsigned short*)alloc(768ull * 768 * 2);
    unsigned short* w1b   = (unsigned short*)alloc(768ull * 768 * 2);
    unsigned short* w2b   = (unsigned short*)alloc(768ull * 768 * 2);
    unsigned short* wopb  = (unsigned short*)alloc(3072ull * 768 * 2);
    float* qnorm          = (float*)alloc(8 * 768 * 4);
    float* qpb            = (float*)alloc(8 * 768 * 4);
    unsigned short* qkb   = (unsigned short*)alloc(64ull * 768 * 2);
    float* tbuf           = (float*)alloc(64 * 4);
    if (off > ws_size) return;  // fail visibly (output stays poisoned)

    // region reuse (dead by the time they're overwritten):
    unsigned short* ctx  = featb;   // featb dead after kv GEMM; ctx 25 MB <= 64 MB
    unsigned short* outb = kvbuf;   // kvbuf dead after attn_ctx; out_pre 100 MB <= 154 MB

    // weight/input casts to bf16
    cast_f2b<<<31360, 256, 0, stream>>>(features, featb, 8028160);
    cast_f2b<<<240,   256, 0, stream>>>(input_proj_w, winb, 61440);
    cast_f2b<<<576,   256, 0, stream>>>(in_proj_w + 2 * 768 * 768, wvb, 147456);  // wv
    cast_f2b<<<576,   256, 0, stream>>>(out_proj_w, woutb, 147456);
    cast_f2b<<<576,   256, 0, stream>>>(ffn_w1, w1b, 147456);
    cast_f2b<<<576,   256, 0, stream>>>(ffn_w2, w2b, 147456);
    cast_f2b<<<2304,  256, 0, stream>>>(output_proj_w, wopb, 589824);

    // batch-independent query path (fp32, tiny)
    ln_rows<768, false, false><<<2, 256, 0, stream>>>(queries, qnorm, ln_q_g, ln_q_b, 8);
    qp_kernel<<<24, 256, 0, stream>>>(qnorm, in_proj_w, in_proj_b, qpb);
    qk_build<<<64, 256, 0, stream>>>(qpb, in_proj_w + 768 * 768, ln_kv_g, qkb, tbuf);

    // kv = features @ Win^T + b  -> bf16 (raw, un-normalized)
    gemm_bf16<0><<<dim3(6, 784), 256, 0, stream>>>(featb, winb, input_proj_b, kvbuf, nullptr, 320, 768);
    // per-row LN stats (rs, rs*mu)
    ln_stats<<<25088, 256, 0, stream>>>(kvbuf, stats, 100352);
    // S = rs*(kv_raw @ qkg^T) - u*t  (LN folded into epilogue)
    gemm_scores<<<784, 256, 0, stream>>>(kvbuf, qkb, stats, tbuf, S);
    // fused: softmax + mix + V/ctx projection (cmix stays in LDS)
    attn_ctx<<<2048, 256, 0, stream>>>(kvbuf, S, stats, ln_kv_g, ln_kv_b, wvb, in_proj_b + 1536, ctx);
    // x = ctx @ out_proj^T + b + queries  -> f32
    gemm_bf16<1><<<dim3(6, 128), 256, 0, stream>>>(ctx, woutb, out_proj_b, x, queries, 768, 768);
    // h = LN(x) -> bf16
    ln_rows<768, false, true><<<4096, 256, 0, stream>>>(x, hn, ln_ff_g, ln_ff_b, 16384);
    // f1 = gelu(h @ w1^T + b1) -> bf16
    gemm_bf16<2><<<dim3(6, 128), 256, 0, stream>>>(hn, w1b, ffn_b1, f1, nullptr, 768, 768);
    // x2 = f1 @ w2^T + b2 + x -> bf16
    gemm_bf16<3><<<dim3(6, 128), 256, 0, stream>>>(f1, w2b, ffn_b2, x2, x, 768, 768);
    // out_pre = x2 @ Wop^T + b -> bf16 (workspace)
    gemm_bf16<0><<<dim3(24, 128), 256, 0, stream>>>(x2, wopb, output_proj_b, outb, nullptr, 768, 3072);
    // final LN: bf16 in -> f32 d_out
    ln_rows<3072, true, false><<<4096, 256, 0, stream>>>(outb, (float*)d_out, final_g, final_b, 16384);
}

// Round 6
// 756.849 us; speedup vs baseline: 1.2137x; 1.2137x over previous
//
#include <hip/hip_runtime.h>
#include <math.h>

typedef __attribute__((ext_vector_type(8))) short short8;
typedef __attribute__((ext_vector_type(8))) unsigned short ushort8;
typedef __attribute__((ext_vector_type(4))) float f32x4;

__device__ __forceinline__ float b2f(unsigned short h) {
    union { unsigned int u; float f; } c; c.u = ((unsigned int)h) << 16; return c.f;
}
__device__ __forceinline__ unsigned short f2b(float x) {
    union { float f; unsigned int u; } c; c.f = x;
    unsigned int r = c.u + 0x7fffu + ((c.u >> 16) & 1u);
    return (unsigned short)(r >> 16);
}

// ---------------- cast f32 -> bf16 (vectorized) ----------------
__global__ __launch_bounds__(256) void cast_f2b(const float* __restrict__ in,
                                                unsigned short* __restrict__ out, int n4) {
    int i = blockIdx.x * 256 + threadIdx.x;
    if (i >= n4) return;
    float4 f = ((const float4*)in)[i];
    ushort4 o; o.x = f2b(f.x); o.y = f2b(f.y); o.z = f2b(f.z); o.w = f2b(f.w);
    ((ushort4*)out)[i] = o;
}

// ---------------- wave-per-row LayerNorm ----------------
template <int DD, bool INB, bool OUTB>
__global__ __launch_bounds__(256) void ln_rows(const void* __restrict__ in_, void* __restrict__ out_,
                                               const float* __restrict__ g, const float* __restrict__ bb,
                                               int nrows) {
    const int wv = threadIdx.x >> 6, l = threadIdx.x & 63;
    const int row = blockIdx.x * 4 + wv;
    if (row >= nrows) return;
    constexpr int NC = DD / 256;
    float v[DD / 64];
    if constexpr (INB) {
        const ushort4* in = (const ushort4*)((const unsigned short*)in_ + (size_t)row * DD);
#pragma unroll
        for (int c = 0; c < NC; ++c) {
            ushort4 u = in[l + 64 * c];
            v[4*c] = b2f(u.x); v[4*c+1] = b2f(u.y); v[4*c+2] = b2f(u.z); v[4*c+3] = b2f(u.w);
        }
    } else {
        const float4* in = (const float4*)((const float*)in_ + (size_t)row * DD);
#pragma unroll
        for (int c = 0; c < NC; ++c) {
            float4 u = in[l + 64 * c];
            v[4*c] = u.x; v[4*c+1] = u.y; v[4*c+2] = u.z; v[4*c+3] = u.w;
        }
    }
    float s = 0.f, s2 = 0.f;
#pragma unroll
    for (int i = 0; i < DD / 64; ++i) { s += v[i]; s2 += v[i] * v[i]; }
#pragma unroll
    for (int o = 32; o > 0; o >>= 1) { s += __shfl_xor(s, o, 64); s2 += __shfl_xor(s2, o, 64); }
    const float mu = s * (1.0f / DD);
    const float var = s2 * (1.0f / DD) - mu * mu;
    const float rs = rsqrtf(var + 1e-5f);
    if constexpr (OUTB) {
        ushort4* out = (ushort4*)((unsigned short*)out_ + (size_t)row * DD);
#pragma unroll
        for (int c = 0; c < NC; ++c) {
            int e = (l + 64 * c) * 4;
            ushort4 o4;
            o4.x = f2b((v[4*c]   - mu) * rs * g[e]   + bb[e]);
            o4.y = f2b((v[4*c+1] - mu) * rs * g[e+1] + bb[e+1]);
            o4.z = f2b((v[4*c+2] - mu) * rs * g[e+2] + bb[e+2]);
            o4.w = f2b((v[4*c+3] - mu) * rs * g[e+3] + bb[e+3]);
            out[l + 64 * c] = o4;
        }
    } else {
        float4* out = (float4*)((float*)out_ + (size_t)row * DD);
#pragma unroll
        for (int c = 0; c < NC; ++c) {
            int e = (l + 64 * c) * 4;
            float4 o4;
            o4.x = (v[4*c]   - mu) * rs * g[e]   + bb[e];
            o4.y = (v[4*c+1] - mu) * rs * g[e+1] + bb[e+1];
            o4.z = (v[4*c+2] - mu) * rs * g[e+2] + bb[e+2];
            o4.w = (v[4*c+3] - mu) * rs * g[e+3] + bb[e+3];
            out[l + 64 * c] = o4;
        }
    }
}

// ---------------- ln_stats: per-row (rs, rs*mu) of raw bf16 kv ----------------
__global__ __launch_bounds__(256) void ln_stats(const unsigned short* __restrict__ kv,
                                                float2* __restrict__ stats, int nrows) {
    const int wv = threadIdx.x >> 6, l = threadIdx.x & 63;
    const int row = blockIdx.x * 4 + wv;
    if (row >= nrows) return;
    const ushort4* in = (const ushort4*)(kv + (size_t)row * 768);
    float s = 0.f, s2 = 0.f;
#pragma unroll
    for (int c = 0; c < 3; ++c) {
        ushort4 u = in[l + 64 * c];
        float a = b2f(u.x), b = b2f(u.y), cc = b2f(u.z), d = b2f(u.w);
        s += a + b + cc + d;
        s2 += a * a + b * b + cc * cc + d * d;
    }
#pragma unroll
    for (int o = 32; o > 0; o >>= 1) { s += __shfl_xor(s, o, 64); s2 += __shfl_xor(s2, o, 64); }
    const float mu = s * (1.0f / 768.0f);
    const float var = s2 * (1.0f / 768.0f) - mu * mu;
    const float rs = rsqrtf(var + 1e-5f);
    if (l == 0) stats[row] = make_float2(rs, rs * mu);
}

// ---------------- qp = LN(queries) @ wq^T + bq ----------------
__global__ __launch_bounds__(256) void qp_kernel(const float* __restrict__ qn, const float* __restrict__ wq,
                                                 const float* __restrict__ bq, float* __restrict__ qp) {
    int q = blockIdx.x / 3;
    int col = (blockIdx.x % 3) * 256 + threadIdx.x;
    const float4* a = (const float4*)(qn + q * 768);
    const float4* wr = (const float4*)(wq + (size_t)col * 768);
    float s = 0.f;
#pragma unroll 8
    for (int k = 0; k < 192; ++k) {
        float4 xx = a[k], yy = wr[k];
        s += xx.x * yy.x + xx.y * yy.y + xx.z * yy.z + xx.w * yy.w;
    }
    qp[q * 768 + col] = s + bq[col];
}

// ---------------- qkg[hq][e] = g[e]*scale*sum_d qp[..]*wk[..][e]; t[hq] = sum_e qkg ----------------
__global__ __launch_bounds__(256) void qk_build(const float* __restrict__ qp, const float* __restrict__ wk,
                                                const float* __restrict__ g,
                                                unsigned short* __restrict__ qkg, float* __restrict__ tout) {
    __shared__ float red[4];
    const int hq = blockIdx.x, h = hq >> 3, q = hq & 7;
    const int tid = threadIdx.x;
    const float* qv = qp + q * 768 + h * 96;
    float tsum = 0.f;
#pragma unroll
    for (int c = 0; c < 3; ++c) {
        int e = tid + 256 * c;
        float s = 0.f;
        for (int d = 0; d < 96; ++d) s += qv[d] * wk[(size_t)(h * 96 + d) * 768 + e];
        unsigned short bv = f2b(s * 0.10206207262f * g[e]);
        qkg[hq * 768 + e] = bv;
        tsum += b2f(bv);
    }
#pragma unroll
    for (int o = 32; o > 0; o >>= 1) tsum += __shfl_xor(tsum, o, 64);
    if ((tid & 63) == 0) red[tid >> 6] = tsum;
    __syncthreads();
    if (tid == 0) tout[hq] = red[0] + red[1] + red[2] + red[3];
}

// ---------------- MFMA GEMM machinery ----------------
__device__ __forceinline__ void gll16(const void* g, void* l) {
    __builtin_amdgcn_global_load_lds((const __attribute__((address_space(1))) unsigned int*)g,
                                     (__attribute__((address_space(3))) unsigned int*)l, 16, 0, 0);
}

template <int ROWS>
__device__ __forceinline__ void stage_rows(const unsigned short* gbase, int ldg,
                                           unsigned short* lds, int tid) {
    int wuni = tid & ~63;
#pragma unroll
    for (int it = 0; it < ROWS / 32; ++it) {
        int s = it * 256 + tid;
        int r = s >> 3, c = s & 7;
        int cc = c ^ (r & 7);  // inverse swizzle on global source; LDS stays gll-linear
        gll16(gbase + (size_t)r * ldg + cc * 8, lds + (size_t)(it * 256 + wuni) * 8);
    }
}

// EPI: 0 bias->bf16 | 1 bias+queries[row&7]->f32 | 2 bias+gelu->bf16 | 3 bias+aux[row]->bf16 | 4 bias->f32
template <int EPI>
__global__ __launch_bounds__(256) void gemm_bf16(
    const unsigned short* __restrict__ A, const unsigned short* __restrict__ W,
    const float* __restrict__ bias, void* __restrict__ out,
    const float* __restrict__ aux, int K, int N) {
    __shared__ __align__(16) unsigned short lA[128 * 64];
    __shared__ __align__(16) unsigned short lB[128 * 64];
    const int tid = threadIdx.x;
    const int l = tid & 63, w = tid >> 6;
    int gx = gridDim.x;
    int lid = blockIdx.y * gx + blockIdx.x;
    int nwg = gx * gridDim.y;
    int idx = (nwg & 7) ? lid : ((lid & 7) * (nwg >> 3) + (lid >> 3));
    const int bm0 = (idx / gx) * 128, bn0 = (idx % gx) * 128;
    const int wm = (w >> 1) * 64, wn = (w & 1) * 64;
    const int l15 = l & 15, lk = l >> 4;
    f32x4 acc[4][4] = {};
    const int nk = K >> 6;
    const unsigned short* Abase = A + (size_t)bm0 * K;
    const unsigned short* Wbase = W + (size_t)bn0 * K;
    for (int kt = 0; kt < nk; ++kt) {
        stage_rows<128>(Abase + kt * 64, K, lA, tid);
        stage_rows<128>(Wbase + kt * 64, K, lB, tid);
        __syncthreads();
        short8 af[4], bf[4];
#pragma unroll
        for (int kk = 0; kk < 2; ++kk) {
#pragma unroll
            for (int mf = 0; mf < 4; ++mf) {
                int r = wm + mf * 16 + l15;
                int c = (kk * 4 + lk) ^ (r & 7);
                af[mf] = *(const short8*)(lA + r * 64 + c * 8);
            }
#pragma unroll
            for (int nf = 0; nf < 4; ++nf) {
                int r = wn + nf * 16 + l15;
                int c = (kk * 4 + lk) ^ (r & 7);
                bf[nf] = *(const short8*)(lB + r * 64 + c * 8);
            }
#pragma unroll
            for (int mf = 0; mf < 4; ++mf)
#pragma unroll
                for (int nf = 0; nf < 4; ++nf)
                    acc[mf][nf] = __builtin_amdgcn_mfma_f32_16x16x32_bf16(af[mf], bf[nf], acc[mf][nf], 0, 0, 0);
        }
        __syncthreads();
    }
    const int row0 = bm0 + wm + (lk << 2);
    const int col0 = bn0 + wn + l15;
#pragma unroll
    for (int nf = 0; nf < 4; ++nf) {
        int col = col0 + nf * 16;
        float bv = bias[col];
#pragma unroll
        for (int mf = 0; mf < 4; ++mf) {
#pragma unroll
            for (int r = 0; r < 4; ++r) {
                int row = row0 + mf * 16 + r;
                float v = acc[mf][nf][r] + bv;
                size_t idx2 = (size_t)row * N + col;
                if constexpr (EPI == 0) {
                    ((unsigned short*)out)[idx2] = f2b(v);
                } else if constexpr (EPI == 1) {
                    v += aux[(row & 7) * N + col];
                    ((float*)out)[idx2] = v;
                } else if constexpr (EPI == 2) {
                    v = 0.5f * v * (1.0f + erff(v * 0.70710678118f));
                    ((unsigned short*)out)[idx2] = f2b(v);
                } else if constexpr (EPI == 3) {
                    v += aux[idx2];
                    ((unsigned short*)out)[idx2] = f2b(v);
                } else {
                    ((float*)out)[idx2] = v;
                }
            }
        }
    }
}

// ---------------- scores GEMM: S = rs_n * (kv_raw @ qkg^T) - u_n * t[hq] ----------------
__global__ __launch_bounds__(256) void gemm_scores(const unsigned short* __restrict__ A,
                                                   const unsigned short* __restrict__ Qk,
                                                   const float2* __restrict__ stats,
                                                   const float* __restrict__ tcol,
                                                   float* __restrict__ S) {
    __shared__ __align__(16) unsigned short lA[128 * 64];
    __shared__ __align__(16) unsigned short lB[64 * 64];
    const int tid = threadIdx.x;
    const int l = tid & 63, w = tid >> 6;
    int lid = blockIdx.x;
    int idx = (lid & 7) * (gridDim.x >> 3) + (lid >> 3);
    const int bm0 = idx * 128;
    const int wm = (w >> 1) * 64, wn = (w & 1) * 32;
    const int l15 = l & 15, lk = l >> 4;
    f32x4 acc[4][2] = {};
    const unsigned short* Abase = A + (size_t)bm0 * 768;
    for (int kt = 0; kt < 12; ++kt) {
        stage_rows<128>(Abase + kt * 64, 768, lA, tid);
        stage_rows<64>(Qk + kt * 64, 768, lB, tid);
        __syncthreads();
        short8 af[4], bf[2];
#pragma unroll
        for (int kk = 0; kk < 2; ++kk) {
#pragma unroll
            for (int mf = 0; mf < 4; ++mf) {
                int r = wm + mf * 16 + l15;
                int c = (kk * 4 + lk) ^ (r & 7);
                af[mf] = *(const short8*)(lA + r * 64 + c * 8);
            }
#pragma unroll
            for (int nf = 0; nf < 2; ++nf) {
                int r = wn + nf * 16 + l15;
                int c = (kk * 4 + lk) ^ (r & 7);
                bf[nf] = *(const short8*)(lB + r * 64 + c * 8);
            }
#pragma unroll
            for (int mf = 0; mf < 4; ++mf)
#pragma unroll
                for (int nf = 0; nf < 2; ++nf)
                    acc[mf][nf] = __builtin_amdgcn_mfma_f32_16x16x32_bf16(af[mf], bf[nf], acc[mf][nf], 0, 0, 0);
        }
        __syncthreads();
    }
    const int row0 = bm0 + wm + (lk << 2);
    const int col0 = wn + l15;
    const float tv0 = tcol[col0], tv1 = tcol[col0 + 16];
#pragma unroll
    for (int mf = 0; mf < 4; ++mf)
#pragma unroll
        for (int r = 0; r < 4; ++r) {
            int row = row0 + mf * 16 + r;
            float2 st = stats[row];
            S[(size_t)row * 64 + col0]      = st.x * acc[mf][0][r] - st.y * tv0;
            S[(size_t)row * 64 + col0 + 16] = st.x * acc[mf][1][r] - st.y * tv1;
        }
}

// ---------------- attn_mix: softmax(S[b]) with rs folded in, mix over RAW kv, LN epilogue ----
// 4 phases of 192 e-columns: LDS = at 8K + kvT 24K + dl ~= 32.4 KB -> 4 blocks/CU.
__global__ __launch_bounds__(256) void attn_mix(const unsigned short* __restrict__ kvr,
                                                const float* __restrict__ S,
                                                const float2* __restrict__ stats,
                                                const float* __restrict__ lg,
                                                const float* __restrict__ lb,
                                                unsigned short* __restrict__ cmix) {
    __shared__ __align__(16) unsigned short at[64 * 64];      // 8 KB  (holds a*rs_n)
    __shared__ __align__(16) unsigned short kvT[192 * 64];    // 24 KB; Sl unions into it
    __shared__ float dl[64];                                  // d[hq] = sum_n a*u_n
    float* Sl = (float*)kvT;                                  // 12.25 KB <= 24 KB
    const int b = blockIdx.x;
    const int t = threadIdx.x, l = t & 63, w = t >> 6;
    const int l15 = l & 15, lk = l >> 4;

    for (int i = t; i < 3136; i += 256) Sl[i] = S[(size_t)b * 3136 + i];
    __syncthreads();
    if (w == 0) {
        float mx = -1e30f;
        for (int n = 0; n < 49; ++n) mx = fmaxf(mx, Sl[n * 64 + l]);
        float sum = 0.f;
        for (int n = 0; n < 49; ++n) sum += __expf(Sl[n * 64 + l] - mx);
        float inv = 1.0f / sum;
        float dacc = 0.f;
#pragma unroll
        for (int c = 0; c < 8; ++c) {
            int cc = c ^ (l & 7);
            for (int j = 0; j < 8; ++j) {
                int n = c * 8 + j;
                float av = 0.f;
                if (n < 49) {
                    float a = __expf(Sl[n * 64 + l] - mx) * inv;
                    float2 st = stats[(size_t)b * 49 + n];
                    av = a * st.x;
                    dacc += a * st.y;
                }
                at[l * 64 + cc * 8 + j] = f2b(av);
            }
        }
        dl[l] = dacc;
    }
    __syncthreads();  // softmax done reading Sl; kvT may now overwrite it

    // hoist dl for this thread's (mf, r) rows
    float dlv[4][4];
#pragma unroll
    for (int mf = 0; mf < 4; ++mf)
#pragma unroll
        for (int r = 0; r < 4; ++r) dlv[mf][r] = dl[mf * 16 + lk * 4 + r];

    const unsigned short* src = kvr + ((size_t)b * 49 + (l < 49 ? l : 0)) * 768;
#pragma unroll 1
    for (int ph = 0; ph < 4; ++ph) {
        // stage kvT[e_local][n] for e_local in [0,192), zero rows n>=49 (NaN guard)
#pragma unroll
        for (int i = 0; i < 6; ++i) {
            int e0 = w * 8 + i * 32;
            ushort8 v = {0, 0, 0, 0, 0, 0, 0, 0};
            if (l < 49) v = *(const ushort8*)(src + ph * 192 + e0);
#pragma unroll
            for (int j = 0; j < 8; ++j) {
                int e = e0 + j;
                kvT[e * 64 + (((l >> 3) ^ (e & 7)) << 3) + (l & 7)] = v[j];
            }
        }
        __syncthreads();
        // mix MFMA: wave w owns e_local in [w*48, w*48+48)
        f32x4 acc[4][3] = {};
#pragma unroll
        for (int ks = 0; ks < 2; ++ks) {
            short8 af[4], bf[3];
#pragma unroll
            for (int mf = 0; mf < 4; ++mf) {
                int r = mf * 16 + l15;
                af[mf] = *(const short8*)(at + r * 64 + (((ks * 4 + lk) ^ (r & 7)) << 3));
            }
#pragma unroll
            for (int nf = 0; nf < 3; ++nf) {
                int er = w * 48 + nf * 16 + l15;
                bf[nf] = *(const short8*)(kvT + er * 64 + (((ks * 4 + lk) ^ (er & 7)) << 3));
            }
#pragma unroll
            for (int mf = 0; mf < 4; ++mf)
#pragma unroll
                for (int nf = 0; nf < 3; ++nf)
                    acc[mf][nf] = __builtin_amdgcn_mfma_f32_16x16x32_bf16(af[mf], bf[nf], acc[mf][nf], 0, 0, 0);
        }
        // write cmix chunk (LN epilogue applied)
#pragma unroll
        for (int nf = 0; nf < 3; ++nf) {
            int e = ph * 192 + w * 48 + nf * 16 + l15;
            float gg = lg[e], bbv = lb[e];
#pragma unroll
            for (int mf = 0; mf < 4; ++mf)
#pragma unroll
                for (int r = 0; r < 4; ++r) {
                    int hq = mf * 16 + lk * 4 + r;
                    float val = gg * (acc[mf][nf][r] - dlv[mf][r]) + bbv;
                    cmix[((size_t)(hq >> 3) * 16384 + b * 8 + (hq & 7)) * 768 + e] = f2b(val);
                }
        }
        __syncthreads();  // mix reads done before next phase restages kvT
    }
}

// ---------------- gemm_ctx: per-h ctx = cmix_h @ wv_h^T + bv_h (16384 x 96, K=768) ----------------
__global__ __launch_bounds__(256) void gemm_ctx(const unsigned short* __restrict__ cmix,
                                                const unsigned short* __restrict__ wvb,
                                                const float* __restrict__ bv,
                                                unsigned short* __restrict__ ctx) {
    __shared__ __align__(16) unsigned short lA[128 * 64];
    __shared__ __align__(16) unsigned short lB[128 * 64];
    const int tid = threadIdx.x;
    const int l = tid & 63, w = tid >> 6;
    const int h = blockIdx.z;
    int yy = blockIdx.y;
    int idx = (yy & 7) * 16 + (yy >> 3);
    const int bm0 = idx * 128;
    const int wm = (w >> 1) * 64, wn = (w & 1) * 64;
    const int l15 = l & 15, lk = l >> 4;
    f32x4 acc[4][4] = {};
    const unsigned short* Abase = cmix + (size_t)h * 16384 * 768 + (size_t)bm0 * 768;
    const unsigned short* Wbase = wvb + (size_t)h * 96 * 768;  // rows 96..127 over-read land in next ws region (finite)
    for (int kt = 0; kt < 12; ++kt) {
        stage_rows<128>(Abase + kt * 64, 768, lA, tid);
        stage_rows<128>(Wbase + kt * 64, 768, lB, tid);
        __syncthreads();
        short8 af[4], bf[4];
#pragma unroll
        for (int kk = 0; kk < 2; ++kk) {
#pragma unroll
            for (int mf = 0; mf < 4; ++mf) {
                int r = wm + mf * 16 + l15;
                int c = (kk * 4 + lk) ^ (r & 7);
                af[mf] = *(const short8*)(lA + r * 64 + c * 8);
            }
#pragma unroll
            for (int nf = 0; nf < 4; ++nf) {
                int r = wn + nf * 16 + l15;
                int c = (kk * 4 + lk) ^ (r & 7);
                bf[nf] = *(const short8*)(lB + r * 64 + c * 8);
            }
#pragma unroll
            for (int mf = 0; mf < 4; ++mf)
#pragma unroll
                for (int nf = 0; nf < 4; ++nf)
                    acc[mf][nf] = __builtin_amdgcn_mfma_f32_16x16x32_bf16(af[mf], bf[nf], acc[mf][nf], 0, 0, 0);
        }
        __syncthreads();
    }
    const int row0 = bm0 + wm + (lk << 2);
    const int col0 = wn + l15;
#pragma unroll
    for (int nf = 0; nf < 4; ++nf) {
        int col = col0 + nf * 16;
        if (col >= 96) continue;
        float bvv = bv[h * 96 + col];
#pragma unroll
        for (int mf = 0; mf < 4; ++mf)
#pragma unroll
            for (int r = 0; r < 4; ++r) {
                int row = row0 + mf * 16 + r;
                ctx[(size_t)row * 768 + h * 96 + col] = f2b(acc[mf][nf][r] + bvv);
            }
    }
}

// ---------------- host ----------------
extern "C" void kernel_launch(void* const* d_in, const int* in_sizes, int n_in,
                              void* d_out, int out_size, void* d_ws, size_t ws_size,
                              hipStream_t stream) {
    (void)in_sizes; (void)n_in; (void)out_size;
    const float* features      = (const float*)d_in[0];
    const float* input_proj_w  = (const float*)d_in[1];
    const float* input_proj_b  = (const float*)d_in[2];
    const float* queries       = (const float*)d_in[3];
    const float* ln_q_g        = (const float*)d_in[4];
    const float* ln_q_b        = (const float*)d_in[5];
    const float* ln_kv_g       = (const float*)d_in[6];
    const float* ln_kv_b       = (const float*)d_in[7];
    const float* in_proj_w     = (const float*)d_in[8];
    const float* in_proj_b     = (const float*)d_in[9];
    const float* out_proj_w    = (const float*)d_in[10];
    const float* out_proj_b    = (const float*)d_in[11];
    const float* ln_ff_g       = (const float*)d_in[12];
    const float* ln_ff_b       = (const float*)d_in[13];
    const float* ffn_w1        = (const float*)d_in[14];
    const float* ffn_b1        = (const float*)d_in[15];
    const float* ffn_w2        = (const float*)d_in[16];
    const float* ffn_b2        = (const float*)d_in[17];
    const float* output_proj_w = (const float*)d_in[18];
    const float* output_proj_b = (const float*)d_in[19];
    const float* final_g       = (const float*)d_in[20];
    const float* final_b       = (const float*)d_in[21];

    char* ws = (char*)d_ws;
    size_t off = 0;
    auto alloc = [&](size_t bytes) -> char* {
        char* r = ws + off; off += (bytes + 255) & ~(size_t)255; return r;
    };
    unsigned short* featb = (unsigned short*)alloc(100352ull * 320 * 2);    // 64 MB
    unsigned short* kvbuf = (unsigned short*)alloc(100352ull * 768 * 2);    // 154 MB (raw kv)
    unsigned short* cmix  = (unsigned short*)alloc(8ull * 16384 * 768 * 2); // 201 MB
    float*          S     = (float*)alloc(100352ull * 64 * 4);              // 26 MB
    float2*         stats = (float2*)alloc(100352ull * 8);                  // 0.8 MB
    unsigned short* winb  = (unsigned short*)alloc(768ull * 320 * 2);
    unsigned short* wvb   = (unsigned short*)alloc(768ull * 768 * 2);
    unsigned short* woutb = (unsigned short*)alloc(768ull * 768 * 2);
    unsigned short* w1b   = (unsigned short*)alloc(768ull * 768 * 2);
    unsigned short* w2b   = (unsigned short*)alloc(768ull * 768 * 2);
    unsigned short* wopb  = (unsigned short*)alloc(3072ull * 768 * 2);
    float* qnorm          = (float*)alloc(8 * 768 * 4);
    float* qpb            = (float*)alloc(8 * 768 * 4);
    unsigned short* qkb   = (unsigned short*)alloc(64ull * 768 * 2);
    float* tbuf           = (float*)alloc(64 * 4);
    if (off > ws_size) return;  // fail visibly (output stays poisoned)

    // region reuse (dead by the time they're overwritten):
    unsigned short* ctx  = featb;                                  // featb dead after kv GEMM
    unsigned short* outb = kvbuf;                                  // kvbuf dead after attn_mix; 100 MB <= 154 MB
    float* x             = (float*)cmix;                           // cmix dead after gemm_ctx
    unsigned short* hn   = (unsigned short*)((char*)cmix + 50331648);
    unsigned short* f1   = (unsigned short*)((char*)cmix + 75497472);
    unsigned short* x2   = (unsigned short*)((char*)cmix + 100663296);

    // weight/input casts to bf16
    cast_f2b<<<31360, 256, 0, stream>>>(features, featb, 8028160);
    cast_f2b<<<240,   256, 0, stream>>>(input_proj_w, winb, 61440);
    cast_f2b<<<576,   256, 0, stream>>>(in_proj_w + 2 * 768 * 768, wvb, 147456);  // wv
    cast_f2b<<<576,   256, 0, stream>>>(out_proj_w, woutb, 147456);
    cast_f2b<<<576,   256, 0, stream>>>(ffn_w1, w1b, 147456);
    cast_f2b<<<576,   256, 0, stream>>>(ffn_w2, w2b, 147456);
    cast_f2b<<<2304,  256, 0, stream>>>(output_proj_w, wopb, 589824);

    // batch-independent query path (fp32, tiny)
    ln_rows<768, false, false><<<2, 256, 0, stream>>>(queries, qnorm, ln_q_g, ln_q_b, 8);
    qp_kernel<<<24, 256, 0, stream>>>(qnorm, in_proj_w, in_proj_b, qpb);
    qk_build<<<64, 256, 0, stream>>>(qpb, in_proj_w + 768 * 768, ln_kv_g, qkb, tbuf);

    // kv = features @ Win^T + b  -> bf16 (raw, un-normalized)
    gemm_bf16<0><<<dim3(6, 784), 256, 0, stream>>>(featb, winb, input_proj_b, kvbuf, nullptr, 320, 768);
    // per-row LN stats (rs, rs*mu)
    ln_stats<<<25088, 256, 0, stream>>>(kvbuf, stats, 100352);
    // S = rs*(kv_raw @ qkg^T) - u*t  (LN folded into epilogue)
    gemm_scores<<<784, 256, 0, stream>>>(kvbuf, qkb, stats, tbuf, S);
    // cmix[h][bq][e] = g[e]*(softmax(S)*rs @ kv_raw - d[hq]) + beta[e]
    attn_mix<<<2048, 256, 0, stream>>>(kvbuf, S, stats, ln_kv_g, ln_kv_b, cmix);
    // ctx = cmix @ wv^T + bv (per h; sum(attn)=1 makes bias exact)
    gemm_ctx<<<dim3(1, 128, 8), 256, 0, stream>>>(cmix, wvb, in_proj_b + 1536, ctx);
    // x = ctx @ out_proj^T + b + queries  -> f32
    gemm_bf16<1><<<dim3(6, 128), 256, 0, stream>>>(ctx, woutb, out_proj_b, x, queries, 768, 768);
    // h = LN(x) -> bf16
    ln_rows<768, false, true><<<4096, 256, 0, stream>>>(x, hn, ln_ff_g, ln_ff_b, 16384);
    // f1 = gelu(h @ w1^T + b1) -> bf16
    gemm_bf16<2><<<dim3(6, 128), 256, 0, stream>>>(hn, w1b, ffn_b1, f1, nullptr, 768, 768);
    // x2 = f1 @ w2^T + b2 + x -> bf16
    gemm_bf16<3><<<dim3(6, 128), 256, 0, stream>>>(f1, w2b, ffn_b2, x2, x, 768, 768);
    // out_pre = x2 @ Wop^T + b -> bf16 (workspace)
    gemm_bf16<0><<<dim3(24, 128), 256, 0, stream>>>(x2, wopb, output_proj_b, outb, nullptr, 768, 3072);
    // final LN: bf16 in -> f32 d_out
    ln_rows<3072, true, false><<<4096, 256, 0, stream>>>(outb, (float*)d_out, final_g, final_b, 16384);
}

// Round 7
// 734.949 us; speedup vs baseline: 1.2498x; 1.0298x over previous
//
#include <hip/hip_runtime.h>
#include <math.h>

typedef __attribute__((ext_vector_type(8))) short short8;
typedef __attribute__((ext_vector_type(8))) unsigned short ushort8;
typedef __attribute__((ext_vector_type(4))) float f32x4;

__device__ __forceinline__ float b2f(unsigned short h) {
    union { unsigned int u; float f; } c; c.u = ((unsigned int)h) << 16; return c.f;
}
__device__ __forceinline__ unsigned short f2b(float x) {
    union { float f; unsigned int u; } c; c.f = x;
    unsigned int r = c.u + 0x7fffu + ((c.u >> 16) & 1u);
    return (unsigned short)(r >> 16);
}

// ---------------- fused f32 -> bf16 casts (all weight/input buffers, one launch) ----------------
// segment block offsets are compile-time: sizes/1024 elements each, /256 blocks
__global__ __launch_bounds__(256) void cast_all(
    const float* __restrict__ f,    unsigned short* __restrict__ fb,
    const float* __restrict__ winw, unsigned short* __restrict__ winb,
    const float* __restrict__ wv,   unsigned short* __restrict__ wvb,
    const float* __restrict__ wo,   unsigned short* __restrict__ wob,
    const float* __restrict__ w1,   unsigned short* __restrict__ w1b,
    const float* __restrict__ w2,   unsigned short* __restrict__ w2b,
    const float* __restrict__ wop,  unsigned short* __restrict__ wopb) {
    int blk = blockIdx.x;
    const float* src; unsigned short* dst; int i;
    if (blk < 31360)      { src = f;    dst = fb;   i = blk * 256 + threadIdx.x; }
    else if (blk < 31600) { src = winw; dst = winb; i = (blk - 31360) * 256 + threadIdx.x; }
    else if (blk < 32176) { src = wv;   dst = wvb;  i = (blk - 31600) * 256 + threadIdx.x; }
    else if (blk < 32752) { src = wo;   dst = wob;  i = (blk - 32176) * 256 + threadIdx.x; }
    else if (blk < 33328) { src = w1;   dst = w1b;  i = (blk - 32752) * 256 + threadIdx.x; }
    else if (blk < 33904) { src = w2;   dst = w2b;  i = (blk - 33328) * 256 + threadIdx.x; }
    else                  { src = wop;  dst = wopb; i = (blk - 33904) * 256 + threadIdx.x; }
    float4 fv = ((const float4*)src)[i];
    ushort4 o; o.x = f2b(fv.x); o.y = f2b(fv.y); o.z = f2b(fv.z); o.w = f2b(fv.w);
    ((ushort4*)dst)[i] = o;
}

// ---------------- wave-per-row LayerNorm ----------------
template <int DD, bool INB, bool OUTB>
__global__ __launch_bounds__(256) void ln_rows(const void* __restrict__ in_, void* __restrict__ out_,
                                               const float* __restrict__ g, const float* __restrict__ bb,
                                               int nrows) {
    const int wv = threadIdx.x >> 6, l = threadIdx.x & 63;
    const int row = blockIdx.x * 4 + wv;
    if (row >= nrows) return;
    constexpr int NC = DD / 256;
    float v[DD / 64];
    if constexpr (INB) {
        const ushort4* in = (const ushort4*)((const unsigned short*)in_ + (size_t)row * DD);
#pragma unroll
        for (int c = 0; c < NC; ++c) {
            ushort4 u = in[l + 64 * c];
            v[4*c] = b2f(u.x); v[4*c+1] = b2f(u.y); v[4*c+2] = b2f(u.z); v[4*c+3] = b2f(u.w);
        }
    } else {
        const float4* in = (const float4*)((const float*)in_ + (size_t)row * DD);
#pragma unroll
        for (int c = 0; c < NC; ++c) {
            float4 u = in[l + 64 * c];
            v[4*c] = u.x; v[4*c+1] = u.y; v[4*c+2] = u.z; v[4*c+3] = u.w;
        }
    }
    float s = 0.f, s2 = 0.f;
#pragma unroll
    for (int i = 0; i < DD / 64; ++i) { s += v[i]; s2 += v[i] * v[i]; }
#pragma unroll
    for (int o = 32; o > 0; o >>= 1) { s += __shfl_xor(s, o, 64); s2 += __shfl_xor(s2, o, 64); }
    const float mu = s * (1.0f / DD);
    const float var = s2 * (1.0f / DD) - mu * mu;
    const float rs = rsqrtf(var + 1e-5f);
    if constexpr (OUTB) {
        ushort4* out = (ushort4*)((unsigned short*)out_ + (size_t)row * DD);
#pragma unroll
        for (int c = 0; c < NC; ++c) {
            int e = (l + 64 * c) * 4;
            ushort4 o4;
            o4.x = f2b((v[4*c]   - mu) * rs * g[e]   + bb[e]);
            o4.y = f2b((v[4*c+1] - mu) * rs * g[e+1] + bb[e+1]);
            o4.z = f2b((v[4*c+2] - mu) * rs * g[e+2] + bb[e+2]);
            o4.w = f2b((v[4*c+3] - mu) * rs * g[e+3] + bb[e+3]);
            out[l + 64 * c] = o4;
        }
    } else {
        float4* out = (float4*)((float*)out_ + (size_t)row * DD);
#pragma unroll
        for (int c = 0; c < NC; ++c) {
            int e = (l + 64 * c) * 4;
            float4 o4;
            o4.x = (v[4*c]   - mu) * rs * g[e]   + bb[e];
            o4.y = (v[4*c+1] - mu) * rs * g[e+1] + bb[e+1];
            o4.z = (v[4*c+2] - mu) * rs * g[e+2] + bb[e+2];
            o4.w = (v[4*c+3] - mu) * rs * g[e+3] + bb[e+3];
            out[l + 64 * c] = o4;
        }
    }
}

// ---------------- ln_stats: per-row (rs, rs*mu) of raw bf16 kv ----------------
__global__ __launch_bounds__(256) void ln_stats(const unsigned short* __restrict__ kv,
                                                float2* __restrict__ stats, int nrows) {
    const int wv = threadIdx.x >> 6, l = threadIdx.x & 63;
    const int row = blockIdx.x * 4 + wv;
    if (row >= nrows) return;
    const ushort4* in = (const ushort4*)(kv + (size_t)row * 768);
    float s = 0.f, s2 = 0.f;
#pragma unroll
    for (int c = 0; c < 3; ++c) {
        ushort4 u = in[l + 64 * c];
        float a = b2f(u.x), b = b2f(u.y), cc = b2f(u.z), d = b2f(u.w);
        s += a + b + cc + d;
        s2 += a * a + b * b + cc * cc + d * d;
    }
#pragma unroll
    for (int o = 32; o > 0; o >>= 1) { s += __shfl_xor(s, o, 64); s2 += __shfl_xor(s2, o, 64); }
    const float mu = s * (1.0f / 768.0f);
    const float var = s2 * (1.0f / 768.0f) - mu * mu;
    const float rs = rsqrtf(var + 1e-5f);
    if (l == 0) stats[row] = make_float2(rs, rs * mu);
}

// ---------------- qp = LN(queries) @ wq^T + bq ----------------
__global__ __launch_bounds__(256) void qp_kernel(const float* __restrict__ qn, const float* __restrict__ wq,
                                                 const float* __restrict__ bq, float* __restrict__ qp) {
    int q = blockIdx.x / 3;
    int col = (blockIdx.x % 3) * 256 + threadIdx.x;
    const float4* a = (const float4*)(qn + q * 768);
    const float4* wr = (const float4*)(wq + (size_t)col * 768);
    float s = 0.f;
#pragma unroll 8
    for (int k = 0; k < 192; ++k) {
        float4 xx = a[k], yy = wr[k];
        s += xx.x * yy.x + xx.y * yy.y + xx.z * yy.z + xx.w * yy.w;
    }
    qp[q * 768 + col] = s + bq[col];
}

// ---------------- qkg[hq][e] = g[e]*scale*sum_d qp[..]*wk[..][e]; t[hq] = sum_e qkg ----------------
__global__ __launch_bounds__(256) void qk_build(const float* __restrict__ qp, const float* __restrict__ wk,
                                                const float* __restrict__ g,
                                                unsigned short* __restrict__ qkg, float* __restrict__ tout) {
    __shared__ float red[4];
    const int hq = blockIdx.x, h = hq >> 3, q = hq & 7;
    const int tid = threadIdx.x;
    const float* qv = qp + q * 768 + h * 96;
    float tsum = 0.f;
#pragma unroll
    for (int c = 0; c < 3; ++c) {
        int e = tid + 256 * c;
        float s = 0.f;
        for (int d = 0; d < 96; ++d) s += qv[d] * wk[(size_t)(h * 96 + d) * 768 + e];
        unsigned short bv = f2b(s * 0.10206207262f * g[e]);
        qkg[hq * 768 + e] = bv;
        tsum += b2f(bv);
    }
#pragma unroll
    for (int o = 32; o > 0; o >>= 1) tsum += __shfl_xor(tsum, o, 64);
    if ((tid & 63) == 0) red[tid >> 6] = tsum;
    __syncthreads();
    if (tid == 0) tout[hq] = red[0] + red[1] + red[2] + red[3];
}

// ---------------- MFMA GEMM machinery ----------------
__device__ __forceinline__ void gll16(const void* g, void* l) {
    __builtin_amdgcn_global_load_lds((const __attribute__((address_space(1))) unsigned int*)g,
                                     (__attribute__((address_space(3))) unsigned int*)l, 16, 0, 0);
}

template <int ROWS>
__device__ __forceinline__ void stage_rows(const unsigned short* gbase, int ldg,
                                           unsigned short* lds, int tid) {
    int wuni = tid & ~63;
#pragma unroll
    for (int it = 0; it < ROWS / 32; ++it) {
        int s = it * 256 + tid;
        int r = s >> 3, c = s & 7;
        int cc = c ^ (r & 7);  // inverse swizzle on global source; LDS stays gll-linear
        gll16(gbase + (size_t)r * ldg + cc * 8, lds + (size_t)(it * 256 + wuni) * 8);
    }
}

// EPI: 0 bias->bf16 | 1 bias+queries[row&7]->f32 | 2 bias+gelu->bf16 | 3 bias+aux[row]->bf16 | 4 bias->f32
template <int EPI>
__global__ __launch_bounds__(256) void gemm_bf16(
    const unsigned short* __restrict__ A, const unsigned short* __restrict__ W,
    const float* __restrict__ bias, void* __restrict__ out,
    const float* __restrict__ aux, int K, int N) {
    __shared__ __align__(16) unsigned short lA[128 * 64];
    __shared__ __align__(16) unsigned short lB[128 * 64];
    const int tid = threadIdx.x;
    const int l = tid & 63, w = tid >> 6;
    int gx = gridDim.x;
    int lid = blockIdx.y * gx + blockIdx.x;
    int nwg = gx * gridDim.y;
    int idx = (nwg & 7) ? lid : ((lid & 7) * (nwg >> 3) + (lid >> 3));
    const int bm0 = (idx / gx) * 128, bn0 = (idx % gx) * 128;
    const int wm = (w >> 1) * 64, wn = (w & 1) * 64;
    const int l15 = l & 15, lk = l >> 4;
    f32x4 acc[4][4] = {};
    const int nk = K >> 6;
    const unsigned short* Abase = A + (size_t)bm0 * K;
    const unsigned short* Wbase = W + (size_t)bn0 * K;
    for (int kt = 0; kt < nk; ++kt) {
        stage_rows<128>(Abase + kt * 64, K, lA, tid);
        stage_rows<128>(Wbase + kt * 64, K, lB, tid);
        __syncthreads();
        short8 af[4], bf[4];
#pragma unroll
        for (int kk = 0; kk < 2; ++kk) {
#pragma unroll
            for (int mf = 0; mf < 4; ++mf) {
                int r = wm + mf * 16 + l15;
                int c = (kk * 4 + lk) ^ (r & 7);
                af[mf] = *(const short8*)(lA + r * 64 + c * 8);
            }
#pragma unroll
            for (int nf = 0; nf < 4; ++nf) {
                int r = wn + nf * 16 + l15;
                int c = (kk * 4 + lk) ^ (r & 7);
                bf[nf] = *(const short8*)(lB + r * 64 + c * 8);
            }
#pragma unroll
            for (int mf = 0; mf < 4; ++mf)
#pragma unroll
                for (int nf = 0; nf < 4; ++nf)
                    acc[mf][nf] = __builtin_amdgcn_mfma_f32_16x16x32_bf16(af[mf], bf[nf], acc[mf][nf], 0, 0, 0);
        }
        __syncthreads();
    }
    const int row0 = bm0 + wm + (lk << 2);
    const int col0 = bn0 + wn + l15;
#pragma unroll
    for (int nf = 0; nf < 4; ++nf) {
        int col = col0 + nf * 16;
        float bv = bias[col];
#pragma unroll
        for (int mf = 0; mf < 4; ++mf) {
#pragma unroll
            for (int r = 0; r < 4; ++r) {
                int row = row0 + mf * 16 + r;
                float v = acc[mf][nf][r] + bv;
                size_t idx2 = (size_t)row * N + col;
                if constexpr (EPI == 0) {
                    ((unsigned short*)out)[idx2] = f2b(v);
                } else if constexpr (EPI == 1) {
                    v += aux[(row & 7) * N + col];
                    ((float*)out)[idx2] = v;
                } else if constexpr (EPI == 2) {
                    v = 0.5f * v * (1.0f + erff(v * 0.70710678118f));
                    ((unsigned short*)out)[idx2] = f2b(v);
                } else if constexpr (EPI == 3) {
                    v += aux[idx2];
                    ((unsigned short*)out)[idx2] = f2b(v);
                } else {
                    ((float*)out)[idx2] = v;
                }
            }
        }
    }
}

// ---------------- scores GEMM: S = rs_n * (kv_raw @ qkg^T) - u_n * t[hq] ----------------
__global__ __launch_bounds__(256) void gemm_scores(const unsigned short* __restrict__ A,
                                                   const unsigned short* __restrict__ Qk,
                                                   const float2* __restrict__ stats,
                                                   const float* __restrict__ tcol,
                                                   float* __restrict__ S) {
    __shared__ __align__(16) unsigned short lA[128 * 64];
    __shared__ __align__(16) unsigned short lB[64 * 64];
    const int tid = threadIdx.x;
    const int l = tid & 63, w = tid >> 6;
    int lid = blockIdx.x;
    int idx = (lid & 7) * (gridDim.x >> 3) + (lid >> 3);
    const int bm0 = idx * 128;
    const int wm = (w >> 1) * 64, wn = (w & 1) * 32;
    const int l15 = l & 15, lk = l >> 4;
    f32x4 acc[4][2] = {};
    const unsigned short* Abase = A + (size_t)bm0 * 768;
    for (int kt = 0; kt < 12; ++kt) {
        stage_rows<128>(Abase + kt * 64, 768, lA, tid);
        stage_rows<64>(Qk + kt * 64, 768, lB, tid);
        __syncthreads();
        short8 af[4], bf[2];
#pragma unroll
        for (int kk = 0; kk < 2; ++kk) {
#pragma unroll
            for (int mf = 0; mf < 4; ++mf) {
                int r = wm + mf * 16 + l15;
                int c = (kk * 4 + lk) ^ (r & 7);
                af[mf] = *(const short8*)(lA + r * 64 + c * 8);
            }
#pragma unroll
            for (int nf = 0; nf < 2; ++nf) {
                int r = wn + nf * 16 + l15;
                int c = (kk * 4 + lk) ^ (r & 7);
                bf[nf] = *(const short8*)(lB + r * 64 + c * 8);
            }
#pragma unroll
            for (int mf = 0; mf < 4; ++mf)
#pragma unroll
                for (int nf = 0; nf < 2; ++nf)
                    acc[mf][nf] = __builtin_amdgcn_mfma_f32_16x16x32_bf16(af[mf], bf[nf], acc[mf][nf], 0, 0, 0);
        }
        __syncthreads();
    }
    const int row0 = bm0 + wm + (lk << 2);
    const int col0 = wn + l15;
    const float tv0 = tcol[col0], tv1 = tcol[col0 + 16];
#pragma unroll
    for (int mf = 0; mf < 4; ++mf)
#pragma unroll
        for (int r = 0; r < 4; ++r) {
            int row = row0 + mf * 16 + r;
            float2 st = stats[row];
            S[(size_t)row * 64 + col0]      = st.x * acc[mf][0][r] - st.y * tv0;
            S[(size_t)row * 64 + col0 + 16] = st.x * acc[mf][1][r] - st.y * tv1;
        }
}

// ---------------- attn_mix v3: swapped-operand MFMA (D[e][hq]) -> packed ushort4 stores ----
// all-wave softmax; T14 reg-prefetch of kv staging; 6 phases of 128 e; LDS ~24.8 KB.
__global__ __launch_bounds__(256) void attn_mix(const unsigned short* __restrict__ kvr,
                                                const float* __restrict__ S,
                                                const float2* __restrict__ stats,
                                                const float* __restrict__ lg,
                                                const float* __restrict__ lb,
                                                unsigned short* __restrict__ cmix) {
    __shared__ __align__(16) unsigned short at[64 * 64];      // 8 KB  (holds a*rs_n)
    __shared__ __align__(16) unsigned short kvT[128 * 64];    // 16 KB; Sl unions into it
    __shared__ float dl[64];                                  // d[hq] = sum_n a*u_n
    float* Sl = (float*)kvT;                                  // 12.25 KB <= 16 KB
    const int b = blockIdx.x;
    const int t = threadIdx.x, l = t & 63, w = t >> 6;
    const int l15 = l & 15, lk = l >> 4;

    for (int i = t; i < 3136; i += 256) Sl[i] = S[(size_t)b * 3136 + i];

    // prefetch phase-0 kv regs (register-only; independent of Sl)
    const unsigned short* src = kvr + ((size_t)b * 49 + (l < 49 ? l : 0)) * 768;
    ushort8 z8 = {0, 0, 0, 0, 0, 0, 0, 0};
    ushort8 va0 = z8, va1 = z8, va2 = z8, va3 = z8;
    if (l < 49) {
        va0 = *(const ushort8*)(src + w * 8);
        va1 = *(const ushort8*)(src + w * 8 + 32);
        va2 = *(const ushort8*)(src + w * 8 + 64);
        va3 = *(const ushort8*)(src + w * 8 + 96);
    }
    __syncthreads();

    // softmax: all waves compute mx/sum/dacc (redundant, parallel); at-write split by wave
    float mx = -1e30f;
    for (int n = 0; n < 49; ++n) mx = fmaxf(mx, Sl[n * 64 + l]);
    float sum = 0.f, dun = 0.f;
    for (int n = 0; n < 49; ++n) {
        float e = __expf(Sl[n * 64 + l] - mx);
        sum += e;
        dun += e * stats[(size_t)b * 49 + n].y;
    }
    float inv = 1.0f / sum;
#pragma unroll
    for (int cd = 0; cd < 2; ++cd) {
        int c = w * 2 + cd;
        int cc = c ^ (l & 7);
#pragma unroll
        for (int j = 0; j < 8; ++j) {
            int n = c * 8 + j;
            float av = 0.f;
            if (n < 49) av = __expf(Sl[n * 64 + l] - mx) * inv * stats[(size_t)b * 49 + n].x;
            at[l * 64 + cc * 8 + j] = f2b(av);
        }
    }
    if (w == 0) dl[l] = dun * inv;
    __syncthreads();  // Sl reads done -> kvT writable; at, dl ready

    float dls[4];
#pragma unroll
    for (int nf = 0; nf < 4; ++nf) dls[nf] = dl[nf * 16 + l15];

#pragma unroll 1
    for (int ph = 0; ph < 6; ++ph) {
        // ds_write current regs to kvT[e][n] (transposed, n-chunk swizzled)
#pragma unroll
        for (int i = 0; i < 4; ++i) {
            ushort8 v = (i == 0) ? va0 : (i == 1) ? va1 : (i == 2) ? va2 : va3;
            int e0 = w * 8 + i * 32;
#pragma unroll
            for (int j = 0; j < 8; ++j) {
                int e = e0 + j;
                kvT[e * 64 + (((l >> 3) ^ (e & 7)) << 3) + (l & 7)] = v[j];
            }
        }
        // T14: prefetch next phase regs (latency hides under barrier + MFMA + stores)
        ushort8 nb0 = z8, nb1 = z8, nb2 = z8, nb3 = z8;
        if (ph < 5 && l < 49) {
            const unsigned short* s2 = src + (ph + 1) * 128 + w * 8;
            nb0 = *(const ushort8*)(s2);
            nb1 = *(const ushort8*)(s2 + 32);
            nb2 = *(const ushort8*)(s2 + 64);
            nb3 = *(const ushort8*)(s2 + 96);
        }
        __syncthreads();
        // mix MFMA, swapped operands: D[m=e][n=hq]; wave owns e_local in [w*32, w*32+32)
        f32x4 acc[2][4] = {};
#pragma unroll
        for (int ks = 0; ks < 2; ++ks) {
            short8 af[2], bf[4];
#pragma unroll
            for (int mf = 0; mf < 2; ++mf) {
                int r = w * 32 + mf * 16 + l15;
                af[mf] = *(const short8*)(kvT + r * 64 + (((ks * 4 + lk) ^ (r & 7)) << 3));
            }
#pragma unroll
            for (int nf = 0; nf < 4; ++nf) {
                int r = nf * 16 + l15;
                bf[nf] = *(const short8*)(at + r * 64 + (((ks * 4 + lk) ^ (r & 7)) << 3));
            }
#pragma unroll
            for (int mf = 0; mf < 2; ++mf)
#pragma unroll
                for (int nf = 0; nf < 4; ++nf)
                    acc[mf][nf] = __builtin_amdgcn_mfma_f32_16x16x32_bf16(af[mf], bf[nf], acc[mf][nf], 0, 0, 0);
        }
        // packed cmix stores (4 consecutive e per lane) with LN epilogue
#pragma unroll
        for (int mf = 0; mf < 2; ++mf) {
            int e0 = ph * 128 + w * 32 + mf * 16 + lk * 4;
            float4 g4 = *(const float4*)(lg + e0);
            float4 b4 = *(const float4*)(lb + e0);
#pragma unroll
            for (int nf = 0; nf < 4; ++nf) {
                int hq = nf * 16 + l15;
                float dv = dls[nf];
                ushort4 o;
                o.x = f2b(g4.x * (acc[mf][nf][0] - dv) + b4.x);
                o.y = f2b(g4.y * (acc[mf][nf][1] - dv) + b4.y);
                o.z = f2b(g4.z * (acc[mf][nf][2] - dv) + b4.z);
                o.w = f2b(g4.w * (acc[mf][nf][3] - dv) + b4.w);
                *(ushort4*)(cmix + ((size_t)(hq >> 3) * 16384 + b * 8 + (hq & 7)) * 768 + e0) = o;
            }
        }
        va0 = nb0; va1 = nb1; va2 = nb2; va3 = nb3;
        __syncthreads();  // mix reads done before next phase's ds_writes
    }
}

// ---------------- gemm_ctx: per-h ctx = cmix_h @ wv_h^T + bv_h (16384 x 96, K=768) ----------------
__global__ __launch_bounds__(256) void gemm_ctx(const unsigned short* __restrict__ cmix,
                                                const unsigned short* __restrict__ wvb,
                                                const float* __restrict__ bv,
                                                unsigned short* __restrict__ ctx) {
    __shared__ __align__(16) unsigned short lA[128 * 64];
    __shared__ __align__(16) unsigned short lB[128 * 64];
    const int tid = threadIdx.x;
    const int l = tid & 63, w = tid >> 6;
    const int h = blockIdx.z;
    int yy = blockIdx.y;
    int idx = (yy & 7) * 16 + (yy >> 3);
    const int bm0 = idx * 128;
    const int wm = (w >> 1) * 64, wn = (w & 1) * 64;
    const int l15 = l & 15, lk = l >> 4;
    f32x4 acc[4][4] = {};
    const unsigned short* Abase = cmix + (size_t)h * 16384 * 768 + (size_t)bm0 * 768;
    const unsigned short* Wbase = wvb + (size_t)h * 96 * 768;  // rows 96..127 over-read land in next ws region (finite)
    for (int kt = 0; kt < 12; ++kt) {
        stage_rows<128>(Abase + kt * 64, 768, lA, tid);
        stage_rows<128>(Wbase + kt * 64, 768, lB, tid);
        __syncthreads();
        short8 af[4], bf[4];
#pragma unroll
        for (int kk = 0; kk < 2; ++kk) {
#pragma unroll
            for (int mf = 0; mf < 4; ++mf) {
                int r = wm + mf * 16 + l15;
                int c = (kk * 4 + lk) ^ (r & 7);
                af[mf] = *(const short8*)(lA + r * 64 + c * 8);
            }
#pragma unroll
            for (int nf = 0; nf < 4; ++nf) {
                int r = wn + nf * 16 + l15;
                int c = (kk * 4 + lk) ^ (r & 7);
                bf[nf] = *(const short8*)(lB + r * 64 + c * 8);
            }
#pragma unroll
            for (int mf = 0; mf < 4; ++mf)
#pragma unroll
                for (int nf = 0; nf < 4; ++nf)
                    acc[mf][nf] = __builtin_amdgcn_mfma_f32_16x16x32_bf16(af[mf], bf[nf], acc[mf][nf], 0, 0, 0);
        }
        __syncthreads();
    }
    const int row0 = bm0 + wm + (lk << 2);
    const int col0 = wn + l15;
#pragma unroll
    for (int nf = 0; nf < 4; ++nf) {
        int col = col0 + nf * 16;
        if (col >= 96) continue;
        float bvv = bv[h * 96 + col];
#pragma unroll
        for (int mf = 0; mf < 4; ++mf)
#pragma unroll
            for (int r = 0; r < 4; ++r) {
                int row = row0 + mf * 16 + r;
                ctx[(size_t)row * 768 + h * 96 + col] = f2b(acc[mf][nf][r] + bvv);
            }
    }
}

// ---------------- host ----------------
extern "C" void kernel_launch(void* const* d_in, const int* in_sizes, int n_in,
                              void* d_out, int out_size, void* d_ws, size_t ws_size,
                              hipStream_t stream) {
    (void)in_sizes; (void)n_in; (void)out_size;
    const float* features      = (const float*)d_in[0];
    const float* input_proj_w  = (const float*)d_in[1];
    const float* input_proj_b  = (const float*)d_in[2];
    const float* queries       = (const float*)d_in[3];
    const float* ln_q_g        = (const float*)d_in[4];
    const float* ln_q_b        = (const float*)d_in[5];
    const float* ln_kv_g       = (const float*)d_in[6];
    const float* ln_kv_b       = (const float*)d_in[7];
    const float* in_proj_w     = (const float*)d_in[8];
    const float* in_proj_b     = (const float*)d_in[9];
    const float* out_proj_w    = (const float*)d_in[10];
    const float* out_proj_b    = (const float*)d_in[11];
    const float* ln_ff_g       = (const float*)d_in[12];
    const float* ln_ff_b       = (const float*)d_in[13];
    const float* ffn_w1        = (const float*)d_in[14];
    const float* ffn_b1        = (const float*)d_in[15];
    const float* ffn_w2        = (const float*)d_in[16];
    const float* ffn_b2        = (const float*)d_in[17];
    const float* output_proj_w = (const float*)d_in[18];
    const float* output_proj_b = (const float*)d_in[19];
    const float* final_g       = (const float*)d_in[20];
    const float* final_b       = (const float*)d_in[21];

    char* ws = (char*)d_ws;
    size_t off = 0;
    auto alloc = [&](size_t bytes) -> char* {
        char* r = ws + off; off += (bytes + 255) & ~(size_t)255; return r;
    };
    unsigned short* featb = (unsigned short*)alloc(100352ull * 320 * 2);    // 64 MB
    unsigned short* kvbuf = (unsigned short*)alloc(100352ull * 768 * 2);    // 154 MB (raw kv)
    unsigned short* cmix  = (unsigned short*)alloc(8ull * 16384 * 768 * 2); // 201 MB
    float*          S     = (float*)alloc(100352ull * 64 * 4);              // 26 MB
    float2*         stats = (float2*)alloc(100352ull * 8);                  // 0.8 MB
    unsigned short* winb  = (unsigned short*)alloc(768ull * 320 * 2);
    unsigned short* wvb   = (unsigned short*)alloc(768ull * 768 * 2);
    unsigned short* woutb = (unsigned short*)alloc(768ull * 768 * 2);
    unsigned short* w1b   = (unsigned short*)alloc(768ull * 768 * 2);
    unsigned short* w2b   = (unsigned short*)alloc(768ull * 768 * 2);
    unsigned short* wopb  = (unsigned short*)alloc(3072ull * 768 * 2);
    float* qnorm          = (float*)alloc(8 * 768 * 4);
    float* qpb            = (float*)alloc(8 * 768 * 4);
    unsigned short* qkb   = (unsigned short*)alloc(64ull * 768 * 2);
    float* tbuf           = (float*)alloc(64 * 4);
    if (off > ws_size) return;  // fail visibly (output stays poisoned)

    // region reuse (dead by the time they're overwritten):
    unsigned short* ctx  = featb;                                  // featb dead after kv GEMM
    unsigned short* outb = kvbuf;                                  // kvbuf dead after attn_mix; 100 MB <= 154 MB
    float* x             = (float*)cmix;                           // cmix dead after gemm_ctx
    unsigned short* hn   = (unsigned short*)((char*)cmix + 50331648);
    unsigned short* f1   = (unsigned short*)((char*)cmix + 75497472);
    unsigned short* x2   = (unsigned short*)((char*)cmix + 100663296);

    // all f32->bf16 casts in one launch
    cast_all<<<36208, 256, 0, stream>>>(features, featb, input_proj_w, winb,
                                        in_proj_w + 2 * 768 * 768, wvb, out_proj_w, woutb,
                                        ffn_w1, w1b, ffn_w2, w2b, output_proj_w, wopb);

    // batch-independent query path (fp32, tiny)
    ln_rows<768, false, false><<<2, 256, 0, stream>>>(queries, qnorm, ln_q_g, ln_q_b, 8);
    qp_kernel<<<24, 256, 0, stream>>>(qnorm, in_proj_w, in_proj_b, qpb);
    qk_build<<<64, 256, 0, stream>>>(qpb, in_proj_w + 768 * 768, ln_kv_g, qkb, tbuf);

    // kv = features @ Win^T + b  -> bf16 (raw, un-normalized)
    gemm_bf16<0><<<dim3(6, 784), 256, 0, stream>>>(featb, winb, input_proj_b, kvbuf, nullptr, 320, 768);
    // per-row LN stats (rs, rs*mu)
    ln_stats<<<25088, 256, 0, stream>>>(kvbuf, stats, 100352);
    // S = rs*(kv_raw @ qkg^T) - u*t  (LN folded into epilogue)
    gemm_scores<<<784, 256, 0, stream>>>(kvbuf, qkb, stats, tbuf, S);
    // cmix[h][bq][e] = g[e]*(softmax(S)*rs @ kv_raw - d[hq]) + beta[e]
    attn_mix<<<2048, 256, 0, stream>>>(kvbuf, S, stats, ln_kv_g, ln_kv_b, cmix);
    // ctx = cmix @ wv^T + bv (per h; sum(attn)=1 makes bias exact)
    gemm_ctx<<<dim3(1, 128, 8), 256, 0, stream>>>(cmix, wvb, in_proj_b + 1536, ctx);
    // x = ctx @ out_proj^T + b + queries  -> f32
    gemm_bf16<1><<<dim3(6, 128), 256, 0, stream>>>(ctx, woutb, out_proj_b, x, queries, 768, 768);
    // h = LN(x) -> bf16
    ln_rows<768, false, true><<<4096, 256, 0, stream>>>(x, hn, ln_ff_g, ln_ff_b, 16384);
    // f1 = gelu(h @ w1^T + b1) -> bf16
    gemm_bf16<2><<<dim3(6, 128), 256, 0, stream>>>(hn, w1b, ffn_b1, f1, nullptr, 768, 768);
    // x2 = f1 @ w2^T + b2 + x -> bf16
    gemm_bf16<3><<<dim3(6, 128), 256, 0, stream>>>(f1, w2b, ffn_b2, x2, x, 768, 768);
    // out_pre = x2 @ Wop^T + b -> bf16 (workspace)
    gemm_bf16<0><<<dim3(24, 128), 256, 0, stream>>>(x2, wopb, output_proj_b, outb, nullptr, 768, 3072);
    // final LN: bf16 in -> f32 d_out
    ln_rows<3072, true, false><<<4096, 256, 0, stream>>>(outb, (float*)d_out, final_g, final_b, 16384);
}